// Round 7
// baseline (571.641 us; speedup 1.0000x reference)
//
#include <hip/hip_runtime.h>
#include <hip/hip_bf16.h>

#define N_NODES 50000
#define N_EDGES 800000
#define N_GRAPHS 256
#define EMB 128
#define HID 256
#define NCLS 10
#define NPAD 50048  // N rounded up to 64

typedef __attribute__((ext_vector_type(4))) float f32x4;
typedef __attribute__((ext_vector_type(8))) short bf16x8;
typedef __attribute__((ext_vector_type(8))) unsigned short u16x8;
typedef unsigned int u32;
#define AS1 __attribute__((address_space(1)))
#define AS3 __attribute__((address_space(3)))

__device__ __forceinline__ int imax(int a, int b) { return a > b ? a : b; }
__device__ __forceinline__ ushort f2bf(float f) {  // round-to-nearest-even
    unsigned u = __float_as_uint(f);
    u += 0x7fffu + ((u >> 16) & 1u);
    return (ushort)(u >> 16);
}
__device__ __forceinline__ float bf2f(ushort h) { return __uint_as_float(((unsigned)h) << 16); }

// A matrices live in a swizzled tiled layout:
//   element (node n, col k) -> tile (n>>6, k>>6), byte within tile:
//   (n&63)*128 + ( ((k&63)*2) ^ ((n&7)<<4) )
// so each (node-tile, k-tile) is a contiguous 8KB chunk that global_load_lds
// copies LINEARLY into LDS; the XOR makes the 16-lane ds_read_b128 column
// reads bank-conflict-free (2-way only).

// ---------------- dtype detection (bf16 vs f32 device tensors) ----------------
__global__ void detect_k(const unsigned short* __restrict__ w, int* flag) {
    if (threadIdx.x == 0 && blockIdx.x == 0) {
        int ok = 1;
        for (int i = 0; i < 64; ++i) {
            float f = __uint_as_float(((unsigned)w[i]) << 16);
            if (!(fabsf(f) < 16.0f)) { ok = 0; break; }
        }
        *flag = ok;
    }
}

// ---------------- weight conversion (bf16 or f32 -> f32 in ws) ----------------
struct ConvArgs { const void* src[9]; long long cum[10]; };

__global__ void convert_k(ConvArgs a, float* __restrict__ dst, const int* __restrict__ flag) {
    int bf = *flag;
    long long total = a.cum[9];
    for (long long i = (long long)blockIdx.x * blockDim.x + threadIdx.x; i < total;
         i += (long long)gridDim.x * blockDim.x) {
        int s = 0;
        while (i >= a.cum[s + 1]) ++s;
        long long j = i - a.cum[s];
        float v;
        if (bf) v = bf2f(((const unsigned short*)a.src[s])[j]);
        else    v = ((const float*)a.src[s])[j];
        dst[i] = v;
    }
}

__global__ void zero_k(int* __restrict__ p, int n) {
    int i = blockIdx.x * blockDim.x + threadIdx.x;
    if (i < n) p[i] = 0;
}

// ---------------- pack W1t [256][384], W2t [256][1024] (transposed, interleaved hi/lo cols) ----------
// A1 cols: [0,256)=M1 interleaved (dim k>>1) ->W1l ; [256,384)=H0 (dim k-256) ->W1r
// A2 cols: [0,512)=M2 interleaved (dim k>>1) ->W2l ; [512,1024)=H1 interleaved ->W2r
__global__ void pack_w_k(const float* __restrict__ Wf, ushort* __restrict__ W1t,
                         ushort* __restrict__ W2t) {
    const int W1L = 5120, W1R = 37888, W2L = 70912, W2R = 136448;
    int i = blockIdx.x * 256 + threadIdx.x;
    if (i < 256 * 384) {
        int n = i / 384, k = i - n * 384;
        float v = (k < 256) ? Wf[W1L + (k >> 1) * 256 + n] : Wf[W1R + (k - 256) * 256 + n];
        W1t[i] = f2bf(v);
    } else if (i < 256 * 384 + 256 * 1024) {
        int j = i - 256 * 384;
        int n = j / 1024, k = j - n * 1024;
        float v = (k < 512) ? Wf[W2L + (k >> 1) * 256 + n]
                            : Wf[W2R + ((k - 512) >> 1) * 256 + n];
        W2t[(size_t)n * 1024 + k] = f2bf(v);
    }
}

// ---------------- embedding gather -> A1 swizzled, k in [256,384) ----------------
__global__ void embed_k(const int* __restrict__ x, const float* __restrict__ emb,
                        char* __restrict__ A1c) {
    int i = blockIdx.x * blockDim.x + threadIdx.x;
    if (i >= N_NODES * 64) return;
    int n = i >> 6, q = i & 63;
    const float2 e = *(const float2*)(emb + x[n] * EMB + q * 2);
    unsigned pk = (unsigned)f2bf(e.x) | ((unsigned)f2bf(e.y) << 16);
    char* hp = A1c + ((size_t)(n >> 6) * 6 + 4 + (q >> 5)) * 8192 + (n & 63) * 128 +
               (((q & 31) * 4) ^ ((n & 7) << 4));
    *(unsigned*)hp = pk;
}

// ---------------- CSR build ----------------
__global__ void hist_edges_k(const int* __restrict__ dst, int* __restrict__ deg) {
    int e = blockIdx.x * blockDim.x + threadIdx.x;
    if (e < N_EDGES) atomicAdd(&deg[dst[e]], 1);
}
__global__ void hist_batch_k(const int* __restrict__ batch, int* __restrict__ gcnt) {
    int i = blockIdx.x * blockDim.x + threadIdx.x;
    if (i < N_NODES) atomicAdd(&gcnt[batch[i]], 1);
}

__global__ void scan_a_k(const int* __restrict__ deg, int* __restrict__ row_ptr,
                         int* __restrict__ bsum) {
    __shared__ int sm[1024];
    int gid = blockIdx.x * 1024 + threadIdx.x;
    int v = (gid < N_NODES) ? deg[gid] : 0;
    sm[threadIdx.x] = v;
    __syncthreads();
    for (int off = 1; off < 1024; off <<= 1) {
        int t = (threadIdx.x >= off) ? sm[threadIdx.x - off] : 0;
        __syncthreads();
        sm[threadIdx.x] += t;
        __syncthreads();
    }
    if (gid <= N_NODES) row_ptr[gid] = sm[threadIdx.x] - v;  // exclusive
    if (threadIdx.x == 1023) bsum[blockIdx.x] = sm[1023];
}

__global__ void scan_b_k(int* __restrict__ bsum, int nb) {
    if (threadIdx.x == 0 && blockIdx.x == 0) {
        int s = 0;
        for (int i = 0; i < nb; ++i) { int v = bsum[i]; bsum[i] = s; s += v; }
    }
}

__global__ void scan_c_k(int* __restrict__ row_ptr, const int* __restrict__ bsum,
                         int* __restrict__ nxt) {
    int gid = blockIdx.x * 1024 + threadIdx.x;
    if (gid <= N_NODES) {
        int v = row_ptr[gid] + bsum[blockIdx.x];
        row_ptr[gid] = v;
        if (gid < N_NODES) nxt[gid] = v;
    }
}

__global__ void scatter_k(const int* __restrict__ src, const int* __restrict__ dst,
                          int* __restrict__ nxt, int* __restrict__ col) {
    int e = blockIdx.x * blockDim.x + threadIdx.x;
    if (e < N_EDGES) {
        int p = atomicAdd(&nxt[dst[e]], 1);
        col[p] = src[e];
    }
}

// ---------------- agg1: mean of neighbor emb rows (L1-resident) -> M1 swizzled ----------
__global__ void agg1_k(const int* __restrict__ row_ptr, const int* __restrict__ colv,
                       const int* __restrict__ x, const float* __restrict__ emb,
                       char* __restrict__ A1c) {
    int w = (blockIdx.x * blockDim.x + threadIdx.x) >> 6;
    int lane = threadIdx.x & 63;
    if (w >= N_NODES) return;
    int s0 = row_ptr[w], s1 = row_ptr[w + 1];
    float a0 = 0.f, a1 = 0.f;
    for (int e = s0; e < s1; ++e) {
        int s = colv[e];
        float2 ev = *(const float2*)(emb + x[s] * EMB + lane * 2);
        a0 += ev.x;
        a1 += ev.y;
    }
    float inv = 1.f / (float)imax(s1 - s0, 1);
    float m0 = a0 * inv, m1 = a1 * inv;
    ushort4 o;
    o.x = f2bf(m0); o.y = f2bf(m0 - bf2f(o.x));
    o.z = f2bf(m1); o.w = f2bf(m1 - bf2f(o.z));
    char* mp = A1c + ((size_t)(w >> 6) * 6 + (lane >> 4)) * 8192 + (w & 63) * 128 +
               (((lane & 15) * 8) ^ ((w & 7) << 4));
    *(ushort4*)mp = o;
}

// ---------------- agg2: mean of neighbor H1 (swizzled ilv hi/lo) -> M2 swizzled ----------------
__global__ void agg2_k(const int* __restrict__ row_ptr, const int* __restrict__ colv,
                       char* __restrict__ A2c) {
    int w = (blockIdx.x * blockDim.x + threadIdx.x) >> 6;
    int lane = threadIdx.x & 63;
    if (w >= N_NODES) return;
    int s0 = row_ptr[w], s1 = row_ptr[w + 1];
    float ac0 = 0.f, ac1 = 0.f, ac2 = 0.f, ac3 = 0.f;
    int ktof = 8 + (lane >> 3);
    int bof = (lane & 7) * 16;
    for (int e = s0; e < s1; ++e) {
        int s = colv[e];
        const char* hp = A2c + ((size_t)(s >> 6) * 16 + ktof) * 8192 + (s & 63) * 128 +
                         (bof ^ ((s & 7) << 4));
        u16x8 hv = *(const u16x8*)hp;
        ac0 += bf2f(hv[0]) + bf2f(hv[1]);
        ac1 += bf2f(hv[2]) + bf2f(hv[3]);
        ac2 += bf2f(hv[4]) + bf2f(hv[5]);
        ac3 += bf2f(hv[6]) + bf2f(hv[7]);
    }
    float inv = 1.f / (float)imax(s1 - s0, 1);
    float m0 = ac0 * inv, m1 = ac1 * inv, m2 = ac2 * inv, m3 = ac3 * inv;
    u16x8 o;
    o[0] = f2bf(m0); o[1] = f2bf(m0 - bf2f(o[0]));
    o[2] = f2bf(m1); o[3] = f2bf(m1 - bf2f(o[2]));
    o[4] = f2bf(m2); o[5] = f2bf(m2 - bf2f(o[4]));
    o[6] = f2bf(m3); o[7] = f2bf(m3 - bf2f(o[6]));
    char* mp = A2c + ((size_t)(w >> 6) * 16 + (lane >> 3)) * 8192 + (w & 63) * 128 +
               (bof ^ ((w & 7) << 4));
    *(u16x8*)mp = o;
}

// ---------------- MFMA GEMM with LDS-staged A, 4-deep async pipeline ----------------
// Block: 64 rows x 256 cols, 4 waves; wave -> cols [wave*64,+64), m-rep 4, n-rep 4.
// A staged via global_load_lds (linear 8KB tiles, pre-swizzled source); counted vmcnt,
// raw s_barrier (no drain). B streamed into registers 1 K-step ahead.
template <int K, bool EPI>
__global__ __launch_bounds__(256, 2) void gemm_mfma_k(
    const char* __restrict__ Aswz, const ushort* __restrict__ Wt,
    const float* __restrict__ bias, ushort* __restrict__ out, char* __restrict__ E) {
    constexpr int NT = K / 64;
    __shared__ __attribute__((aligned(16))) char As[4 * 8192];
    const int tid = threadIdx.x, wave = tid >> 6, lane = tid & 63;
    const int row0 = blockIdx.x * 64, col0 = wave * 64;
    const char* Ab = Aswz + (size_t)blockIdx.x * NT * 8192 + tid * 16;
    const ushort* Wp = Wt + (size_t)(col0 + (lane & 15)) * K + ((lane >> 4) * 8);

    // per-(kk-half, m) swizzled LDS byte offsets
    int offA[2][4];
#pragma unroll
    for (int h = 0; h < 2; ++h)
#pragma unroll
        for (int m = 0; m < 4; ++m) {
            int r = (lane & 15) + m * 16;
            int b = h * 64 + (lane >> 4) * 16;
            offA[h][m] = r * 128 + (b ^ ((r & 7) << 4));
        }

    f32x4 acc[4][4];
#pragma unroll
    for (int m = 0; m < 4; ++m)
#pragma unroll
        for (int n = 0; n < 4; ++n) acc[m][n] = (f32x4){0.f, 0.f, 0.f, 0.f};

    bf16x8 B0[8], B1[8];

#define STAGE(t)                                                                     \
    {                                                                                \
        const char* _s = Ab + (size_t)(t) * 8192;                                    \
        char* _d = As + ((t) & 3) * 8192 + tid * 16;                                 \
        __builtin_amdgcn_global_load_lds((const AS1 u32*)_s, (AS3 u32*)_d, 16, 0, 0);\
        __builtin_amdgcn_global_load_lds((const AS1 u32*)(_s + 4096),                \
                                         (AS3 u32*)(_d + 4096), 16, 0, 0);           \
    }
#define LOADB(t, Bf)                                                                 \
    {                                                                                \
        _Pragma("unroll") for (int n = 0; n < 4; ++n) {                              \
            Bf[n]     = *(const bf16x8*)(Wp + (size_t)n * 16 * K + (t) * 64);        \
            Bf[4 + n] = *(const bf16x8*)(Wp + (size_t)n * 16 * K + (t) * 64 + 32);   \
        }                                                                            \
    }
#define COMP(p, Bf)                                                                  \
    {                                                                                \
        const char* _b = As + (p) * 8192;                                            \
        _Pragma("unroll") for (int h = 0; h < 2; ++h) {                              \
            bf16x8 _a[4];                                                            \
            _Pragma("unroll") for (int m = 0; m < 4; ++m)                            \
                _a[m] = *(const bf16x8*)(_b + offA[h][m]);                           \
            _Pragma("unroll") for (int m = 0; m < 4; ++m)                            \
                _Pragma("unroll") for (int n = 0; n < 4; ++n)                        \
                    acc[m][n] = __builtin_amdgcn_mfma_f32_16x16x32_bf16(             \
                        _a[m], Bf[h * 4 + n], acc[m][n], 0, 0, 0);                   \
        }                                                                            \
    }
#define WAITBAR()                                                                    \
    {                                                                                \
        asm volatile("s_waitcnt vmcnt(12)" ::: "memory");                            \
        __builtin_amdgcn_s_barrier();                                                \
        asm volatile("" ::: "memory");                                               \
    }

    STAGE(0);
    LOADB(0, B0);
    STAGE(1);
    STAGE(2);

#pragma unroll 1
    for (int t = 0; t < NT; t += 2) {
        WAITBAR();                       // buf[t] ready across all waves
        if (t + 3 < NT) STAGE(t + 3);
        LOADB(t + 1, B1);                // t+1 <= NT-1 always
        COMP(t & 3, B0);
        WAITBAR();                       // buf[t+1] ready
        if (t + 4 < NT) STAGE(t + 4);
        if (t + 2 < NT) LOADB(t + 2, B0);
        COMP((t + 1) & 3, B1);
    }

    float bv[4];
#pragma unroll
    for (int n = 0; n < 4; ++n) bv[n] = bias[col0 + n * 16 + (lane & 15)];
    int rbase = row0 + ((lane >> 4) * 4);
    int cbase = col0 + (lane & 15);
#pragma unroll
    for (int m = 0; m < 4; ++m)
#pragma unroll
        for (int n = 0; n < 4; ++n)
#pragma unroll
            for (int r = 0; r < 4; ++r) {
                int row = rbase + m * 16 + r;
                if (row < N_NODES) {
                    float v = acc[m][n][r] + bv[n];
                    v = v > 0.f ? v : 0.f;
                    int colc = cbase + n * 16;
                    if (EPI) {
                        ushort h = f2bf(v);
                        ushort l = f2bf(v - bf2f(h));
                        char* ep = E + ((size_t)(row >> 6) * 16 + 8 + (colc >> 5)) * 8192 +
                                   (row & 63) * 128 + (((colc & 31) * 4) ^ ((row & 7) << 4));
                        *(unsigned*)ep = (unsigned)h | ((unsigned)l << 16);
                    } else {
                        out[(size_t)row * 256 + colc] = f2bf(v);
                    }
                }
            }
#undef STAGE
#undef LOADB
#undef COMP
#undef WAITBAR
}

// ---------------- sorted-batch graph pooling over bf16 H2 ----------------
__global__ void pool_k(const ushort* __restrict__ H2, const int* __restrict__ batch,
                       float* __restrict__ g_acc) {
    int t = threadIdx.x;
    int i0 = blockIdx.x * 256;
    if (i0 >= N_NODES) return;
    int iend = i0 + 256 < N_NODES ? i0 + 256 : N_NODES;
    int cur = batch[i0];
    float run = 0.f;
    for (int i = i0; i < iend; ++i) {
        int b = batch[i];
        if (b != cur) {
            atomicAdd(&g_acc[cur * HID + t], run);
            run = 0.f;
            cur = b;
        }
        run += bf2f(H2[(size_t)i * HID + t]);
    }
    atomicAdd(&g_acc[cur * HID + t], run);
}

// ---------------- final: out = (g_acc/cnt) @ Wo + bo ----------------
__global__ void final_k(const float* __restrict__ g_acc, const int* __restrict__ gcnt,
                        const float* __restrict__ Wo, const float* __restrict__ bo,
                        void* __restrict__ out, const int* __restrict__ flag) {
    __shared__ float gm[HID];
    __shared__ float red[HID];
    int g = blockIdx.x, t = threadIdx.x;
    float inv = 1.0f / (float)imax(gcnt[g], 1);
    gm[t] = g_acc[g * HID + t] * inv;
    __syncthreads();
    int bf = *flag;
    for (int c = 0; c < NCLS; ++c) {
        red[t] = gm[t] * Wo[t * NCLS + c];
        __syncthreads();
        for (int s = HID / 2; s > 0; s >>= 1) {
            if (t < s) red[t] += red[t + s];
            __syncthreads();
        }
        if (t == 0) {
            float o = red[0] + bo[c];
            if (bf) ((__hip_bfloat16*)out)[g * NCLS + c] = __float2bfloat16(o);
            else    ((float*)out)[g * NCLS + c] = o;
        }
        __syncthreads();
    }
}

extern "C" void kernel_launch(void* const* d_in, const int* in_sizes, int n_in,
                              void* d_out, int out_size, void* d_ws, size_t ws_size,
                              hipStream_t stream) {
    const int* x     = (const int*)d_in[0];
    const int* ei    = (const int*)d_in[1];
    const int* batch = (const int*)d_in[2];
    const int* srcp = ei;
    const int* dstp = ei + N_EDGES;

    // ---- ws layout ----
    char* w = (char*)d_ws;
    auto alloc = [&](size_t bytes) -> char* {
        char* p = w;
        w += (bytes + 255) & ~(size_t)255;
        return p;
    };
    int* flag = (int*)alloc(256);
    const int ZWORDS = N_NODES + N_GRAPHS + N_GRAPHS * HID;  // deg | gcnt | g_acc
    int* zbase = (int*)alloc((size_t)ZWORDS * 4);
    int* deg = zbase;
    int* gcnt = zbase + N_NODES;
    float* g_acc = (float*)(zbase + N_NODES + N_GRAPHS);
    int* row_ptr = (int*)alloc((size_t)(N_NODES + 1) * 4);
    int* nxt     = (int*)alloc((size_t)N_NODES * 4);
    int* bsum    = (int*)alloc(256);
    int* col     = (int*)alloc((size_t)N_EDGES * 4);
    float* Wf    = (float*)alloc((size_t)204810 * 4);
    ushort* W1t  = (ushort*)alloc((size_t)256 * 384 * 2);
    ushort* W2t  = (ushort*)alloc((size_t)256 * 1024 * 2);
    char* A1c    = alloc((size_t)(NPAD / 64) * 6 * 8192);   // swizzled [M1 ilv | H0]
    char* A2c    = alloc((size_t)(NPAD / 64) * 16 * 8192);  // swizzled [M2 ilv | H1 ilv]
    alloc(4096);                                            // pad
    ushort* H2 = (ushort*)A1c;  // A1 dead after gemm1; reuse for bf16 H2 [N][256]

    const long long cum[10] = {0, 5120, 37888, 70656, 70912, 136448, 201984, 202240, 204800, 204810};
    float* embW = Wf + cum[0];
    float* b1   = Wf + cum[3];
    float* b2   = Wf + cum[6];
    float* Wo   = Wf + cum[7];
    float* bo   = Wf + cum[8];

    // ---- pipeline ----
    detect_k<<<1, 64, 0, stream>>>((const unsigned short*)d_in[3], flag);
    zero_k<<<(ZWORDS + 255) / 256, 256, 0, stream>>>(zbase, ZWORDS);

    ConvArgs ca;
    for (int i = 0; i < 9; ++i) ca.src[i] = d_in[3 + i];
    for (int i = 0; i < 10; ++i) ca.cum[i] = cum[i];
    convert_k<<<801, 256, 0, stream>>>(ca, Wf, flag);

    pack_w_k<<<(256 * 384 + 256 * 1024 + 255) / 256, 256, 0, stream>>>(Wf, W1t, W2t);
    embed_k<<<(N_NODES * 64 + 255) / 256, 256, 0, stream>>>(x, embW, A1c);

    hist_edges_k<<<(N_EDGES + 255) / 256, 256, 0, stream>>>(dstp, deg);
    hist_batch_k<<<(N_NODES + 255) / 256, 256, 0, stream>>>(batch, gcnt);

    const int SBLK = (N_NODES + 1 + 1023) / 1024;  // 49
    scan_a_k<<<SBLK, 1024, 0, stream>>>(deg, row_ptr, bsum);
    scan_b_k<<<1, 64, 0, stream>>>(bsum, SBLK);
    scan_c_k<<<SBLK, 1024, 0, stream>>>(row_ptr, bsum, nxt);
    scatter_k<<<(N_EDGES + 255) / 256, 256, 0, stream>>>(srcp, dstp, nxt, col);

    const int GB = NPAD / 64;  // 782
    // layer 1
    agg1_k<<<(N_NODES * 64 + 255) / 256, 256, 0, stream>>>(row_ptr, col, x, embW, A1c);
    gemm_mfma_k<384, true><<<GB, 256, 0, stream>>>(A1c, W1t, b1, nullptr, A2c);
    // layer 2
    agg2_k<<<(N_NODES * 64 + 255) / 256, 256, 0, stream>>>(row_ptr, col, A2c);
    gemm_mfma_k<1024, false><<<GB, 256, 0, stream>>>(A2c, W2t, b2, H2, nullptr);

    // pooling + classifier
    pool_k<<<(N_NODES + 255) / 256, 256, 0, stream>>>(H2, batch, g_acc);
    final_k<<<N_GRAPHS, HID, 0, stream>>>(g_acc, gcnt, Wo, bo, d_out, flag);

    (void)in_sizes; (void)n_in; (void)out_size; (void)ws_size;
}

// Round 8
// 508.880 us; speedup vs baseline: 1.1233x; 1.1233x over previous
//
#include <hip/hip_runtime.h>
#include <hip/hip_bf16.h>

#define N_NODES 50000
#define N_EDGES 800000
#define N_GRAPHS 256
#define EMB 128
#define HID 256
#define NCLS 10
#define NPAD 50048  // N rounded up to 64

typedef __attribute__((ext_vector_type(4))) float f32x4;
typedef __attribute__((ext_vector_type(8))) short bf16x8;
typedef __attribute__((ext_vector_type(8))) _Float16 f16x8;
typedef __attribute__((ext_vector_type(4))) _Float16 f16x4;
typedef unsigned int u32;
#define AS1 __attribute__((address_space(1)))
#define AS3 __attribute__((address_space(3)))

__device__ __forceinline__ int imax(int a, int b) { return a > b ? a : b; }
__device__ __forceinline__ ushort f2bf(float f) {  // round-to-nearest-even
    unsigned u = __float_as_uint(f);
    u += 0x7fffu + ((u >> 16) & 1u);
    return (ushort)(u >> 16);
}
__device__ __forceinline__ float bf2f(ushort h) { return __uint_as_float(((unsigned)h) << 16); }

// A matrices live in a swizzled tiled layout:
//   element (node n, col k) -> tile (n>>6, k>>6), byte within tile:
//   (n&63)*128 + ( ((k&63)*2) ^ ((n&7)<<4) )
// Each (node-tile, k-tile) is a contiguous 8KB chunk that global_load_lds copies
// LINEARLY into LDS; the XOR makes 16-lane ds_read_b128 column reads conflict-free.
//
// A1 (layer1, K=384, bf16): k-tiles 0-3 = M1 hi/lo interleaved, 4-5 = H0.
// A2 (layer2, K=512, f16):  k-tiles 0-3 = M2 (dims 0-255), 4-7 = H1 (dims 0-255).

// ---------------- dtype detection (bf16 vs f32 device tensors) ----------------
__global__ void detect_k(const unsigned short* __restrict__ w, int* flag) {
    if (threadIdx.x == 0 && blockIdx.x == 0) {
        int ok = 1;
        for (int i = 0; i < 64; ++i) {
            float f = __uint_as_float(((unsigned)w[i]) << 16);
            if (!(fabsf(f) < 16.0f)) { ok = 0; break; }
        }
        *flag = ok;
    }
}

// ---------------- weight conversion (bf16 or f32 -> f32 in ws) ----------------
struct ConvArgs { const void* src[9]; long long cum[10]; };

__global__ void convert_k(ConvArgs a, float* __restrict__ dst, const int* __restrict__ flag) {
    int bf = *flag;
    long long total = a.cum[9];
    for (long long i = (long long)blockIdx.x * blockDim.x + threadIdx.x; i < total;
         i += (long long)gridDim.x * blockDim.x) {
        int s = 0;
        while (i >= a.cum[s + 1]) ++s;
        long long j = i - a.cum[s];
        float v;
        if (bf) v = bf2f(((const unsigned short*)a.src[s])[j]);
        else    v = ((const float*)a.src[s])[j];
        dst[i] = v;
    }
}

__global__ void zero_k(int* __restrict__ p, int n) {
    int i = blockIdx.x * blockDim.x + threadIdx.x;
    if (i < n) p[i] = 0;
}

// ---------------- pack W1t [256][384] bf16, W2t [256][512] f16 (transposed) ----------
// W1t k: [0,256)=M1 ilv hi/lo (dim k>>1) ->W1l ; [256,384)=H0 (dim k-256) ->W1r
// W2t k: [0,256)=M2 (dim k) ->W2l ; [256,512)=H1 (dim k-256) ->W2r
__global__ void pack_w_k(const float* __restrict__ Wf, ushort* __restrict__ W1t,
                         _Float16* __restrict__ W2t) {
    const int W1L = 5120, W1R = 37888, W2L = 70912, W2R = 136448;
    int i = blockIdx.x * 256 + threadIdx.x;
    if (i < 256 * 384) {
        int n = i / 384, k = i - n * 384;
        float v = (k < 256) ? Wf[W1L + (k >> 1) * 256 + n] : Wf[W1R + (k - 256) * 256 + n];
        W1t[i] = f2bf(v);
    } else if (i < 256 * 384 + 256 * 512) {
        int j = i - 256 * 384;
        int n = j >> 9, k = j & 511;
        float v = (k < 256) ? Wf[W2L + k * 256 + n] : Wf[W2R + (k - 256) * 256 + n];
        W2t[(size_t)n * 512 + k] = (_Float16)v;
    }
}

// ---------------- embedding gather -> A1 swizzled, k in [256,384) ----------------
__global__ void embed_k(const int* __restrict__ x, const float* __restrict__ emb,
                        char* __restrict__ A1c) {
    int i = blockIdx.x * blockDim.x + threadIdx.x;
    if (i >= N_NODES * 64) return;
    int n = i >> 6, q = i & 63;
    const float2 e = *(const float2*)(emb + x[n] * EMB + q * 2);
    unsigned pk = (unsigned)f2bf(e.x) | ((unsigned)f2bf(e.y) << 16);
    char* hp = A1c + ((size_t)(n >> 6) * 6 + 4 + (q >> 5)) * 8192 + (n & 63) * 128 +
               (((q & 31) * 4) ^ ((n & 7) << 4));
    *(unsigned*)hp = pk;
}

// ---------------- CSR build ----------------
__global__ void hist_edges_k(const int* __restrict__ dst, int* __restrict__ deg) {
    int e = blockIdx.x * blockDim.x + threadIdx.x;
    if (e < N_EDGES) atomicAdd(&deg[dst[e]], 1);
}
__global__ void hist_batch_k(const int* __restrict__ batch, int* __restrict__ gcnt) {
    int i = blockIdx.x * blockDim.x + threadIdx.x;
    if (i < N_NODES) atomicAdd(&gcnt[batch[i]], 1);
}

__global__ void scan_a_k(const int* __restrict__ deg, int* __restrict__ row_ptr,
                         int* __restrict__ bsum) {
    __shared__ int sm[1024];
    int gid = blockIdx.x * 1024 + threadIdx.x;
    int v = (gid < N_NODES) ? deg[gid] : 0;
    sm[threadIdx.x] = v;
    __syncthreads();
    for (int off = 1; off < 1024; off <<= 1) {
        int t = (threadIdx.x >= off) ? sm[threadIdx.x - off] : 0;
        __syncthreads();
        sm[threadIdx.x] += t;
        __syncthreads();
    }
    if (gid <= N_NODES) row_ptr[gid] = sm[threadIdx.x] - v;  // exclusive
    if (threadIdx.x == 1023) bsum[blockIdx.x] = sm[1023];
}

__global__ void scan_b_k(int* __restrict__ bsum, int nb) {
    if (threadIdx.x == 0 && blockIdx.x == 0) {
        int s = 0;
        for (int i = 0; i < nb; ++i) { int v = bsum[i]; bsum[i] = s; s += v; }
    }
}

__global__ void scan_c_k(int* __restrict__ row_ptr, const int* __restrict__ bsum,
                         int* __restrict__ nxt) {
    int gid = blockIdx.x * 1024 + threadIdx.x;
    if (gid <= N_NODES) {
        int v = row_ptr[gid] + bsum[blockIdx.x];
        row_ptr[gid] = v;
        if (gid < N_NODES) nxt[gid] = v;
    }
}

__global__ void scatter_k(const int* __restrict__ src, const int* __restrict__ dst,
                          int* __restrict__ nxt, int* __restrict__ col) {
    int e = blockIdx.x * blockDim.x + threadIdx.x;
    if (e < N_EDGES) {
        int p = atomicAdd(&nxt[dst[e]], 1);
        col[p] = src[e];
    }
}

// ---------------- agg1: mean of neighbor emb rows (L1-resident) -> M1 swizzled ----------
__global__ void agg1_k(const int* __restrict__ row_ptr, const int* __restrict__ colv,
                       const int* __restrict__ x, const float* __restrict__ emb,
                       char* __restrict__ A1c) {
    int w = (blockIdx.x * blockDim.x + threadIdx.x) >> 6;
    int lane = threadIdx.x & 63;
    if (w >= N_NODES) return;
    int s0 = row_ptr[w], s1 = row_ptr[w + 1];
    float a0 = 0.f, a1 = 0.f;
    for (int e = s0; e < s1; ++e) {
        int s = colv[e];
        float2 ev = *(const float2*)(emb + x[s] * EMB + lane * 2);
        a0 += ev.x;
        a1 += ev.y;
    }
    float inv = 1.f / (float)imax(s1 - s0, 1);
    float m0 = a0 * inv, m1 = a1 * inv;
    ushort4 o;
    o.x = f2bf(m0); o.y = f2bf(m0 - bf2f(o.x));
    o.z = f2bf(m1); o.w = f2bf(m1 - bf2f(o.z));
    char* mp = A1c + ((size_t)(w >> 6) * 6 + (lane >> 4)) * 8192 + (w & 63) * 128 +
               (((lane & 15) * 8) ^ ((w & 7) << 4));
    *(ushort4*)mp = o;
}

// ---------------- agg2: mean of neighbor H1 (f16, swizzled tiles 4-7) -> M2 f16 (tiles 0-3) ----
__global__ void agg2_k(const int* __restrict__ row_ptr, const int* __restrict__ colv,
                       char* __restrict__ A2c) {
    int w = (blockIdx.x * blockDim.x + threadIdx.x) >> 6;
    int lane = threadIdx.x & 63;
    if (w >= N_NODES) return;
    int s0 = row_ptr[w], s1 = row_ptr[w + 1];
    float ac0 = 0.f, ac1 = 0.f, ac2 = 0.f, ac3 = 0.f;
    int ktof = 4 + (lane >> 4);   // H1 dim d = lane*4 -> k-tile 4 + (d>>6)
    int bof = (lane & 15) * 8;    // (d&63)*2 bytes
    for (int e = s0; e < s1; ++e) {
        int s = colv[e];
        const char* hp = A2c + ((size_t)(s >> 6) * 8 + ktof) * 8192 + (s & 63) * 128 +
                         (bof ^ ((s & 7) << 4));
        f16x4 hv = *(const f16x4*)hp;
        ac0 += (float)hv[0];
        ac1 += (float)hv[1];
        ac2 += (float)hv[2];
        ac3 += (float)hv[3];
    }
    float inv = 1.f / (float)imax(s1 - s0, 1);
    f16x4 o;
    o[0] = (_Float16)(ac0 * inv);
    o[1] = (_Float16)(ac1 * inv);
    o[2] = (_Float16)(ac2 * inv);
    o[3] = (_Float16)(ac3 * inv);
    char* mp = A2c + ((size_t)(w >> 6) * 8 + (ktof - 4)) * 8192 + (w & 63) * 128 +
               (bof ^ ((w & 7) << 4));
    *(f16x4*)mp = o;
}

// ---------------- MFMA GEMM with LDS-staged A, 4-deep async pipeline ----------------
// Block: 64 rows x 256 cols, 4 waves; wave -> cols [wave*64,+64), m-rep 4, n-rep 4.
// A staged via global_load_lds (linear 8KB tiles, pre-swizzled source); counted vmcnt,
// raw s_barrier (no drain). B streamed into registers 1 K-step ahead.
// F16: use f16 MFMA (A/B bits are f16). EPI: 1 = write f16 swizzled into E k-tiles 4-7
// (NT_E=8 layout); 0 = write f16 linear [N][256] to out.
template <int K, int EPI, bool F16>
__global__ __launch_bounds__(256, 2) void gemm_mfma_k(
    const char* __restrict__ Aswz, const ushort* __restrict__ Wt,
    const float* __restrict__ bias, _Float16* __restrict__ out, char* __restrict__ E) {
    constexpr int NT = K / 64;
    __shared__ __attribute__((aligned(16))) char As[4 * 8192];
    const int tid = threadIdx.x, wave = tid >> 6, lane = tid & 63;
    const int row0 = blockIdx.x * 64, col0 = wave * 64;
    const char* Ab = Aswz + (size_t)blockIdx.x * NT * 8192 + tid * 16;
    const ushort* Wp = Wt + (size_t)(col0 + (lane & 15)) * K + ((lane >> 4) * 8);

    // per-(kk-half, m) swizzled LDS byte offsets
    int offA[2][4];
#pragma unroll
    for (int h = 0; h < 2; ++h)
#pragma unroll
        for (int m = 0; m < 4; ++m) {
            int r = (lane & 15) + m * 16;
            int b = h * 64 + (lane >> 4) * 16;
            offA[h][m] = r * 128 + (b ^ ((r & 7) << 4));
        }

    f32x4 acc[4][4];
#pragma unroll
    for (int m = 0; m < 4; ++m)
#pragma unroll
        for (int n = 0; n < 4; ++n) acc[m][n] = (f32x4){0.f, 0.f, 0.f, 0.f};

    bf16x8 B0[8], B1[8];

#define STAGE(t)                                                                     \
    {                                                                                \
        const char* _s = Ab + (size_t)(t) * 8192;                                    \
        char* _d = As + ((t) & 3) * 8192 + tid * 16;                                 \
        __builtin_amdgcn_global_load_lds((const AS1 u32*)_s, (AS3 u32*)_d, 16, 0, 0);\
        __builtin_amdgcn_global_load_lds((const AS1 u32*)(_s + 4096),                \
                                         (AS3 u32*)(_d + 4096), 16, 0, 0);           \
    }
#define LOADB(t, Bf)                                                                 \
    {                                                                                \
        _Pragma("unroll") for (int n = 0; n < 4; ++n) {                              \
            Bf[n]     = *(const bf16x8*)(Wp + (size_t)n * 16 * K + (t) * 64);        \
            Bf[4 + n] = *(const bf16x8*)(Wp + (size_t)n * 16 * K + (t) * 64 + 32);   \
        }                                                                            \
    }
#define COMP(p, Bf)                                                                  \
    {                                                                                \
        const char* _b = As + (p) * 8192;                                            \
        _Pragma("unroll") for (int h = 0; h < 2; ++h) {                              \
            bf16x8 _a[4];                                                            \
            _Pragma("unroll") for (int m = 0; m < 4; ++m)                            \
                _a[m] = *(const bf16x8*)(_b + offA[h][m]);                           \
            _Pragma("unroll") for (int m = 0; m < 4; ++m)                            \
                _Pragma("unroll") for (int n = 0; n < 4; ++n) {                      \
                    if (F16)                                                         \
                        acc[m][n] = __builtin_amdgcn_mfma_f32_16x16x32_f16(          \
                            __builtin_bit_cast(f16x8, _a[m]),                        \
                            __builtin_bit_cast(f16x8, Bf[h * 4 + n]), acc[m][n],     \
                            0, 0, 0);                                                \
                    else                                                             \
                        acc[m][n] = __builtin_amdgcn_mfma_f32_16x16x32_bf16(         \
                            _a[m], Bf[h * 4 + n], acc[m][n], 0, 0, 0);               \
                }                                                                    \
        }                                                                            \
    }
#define WAITBAR()                                                                    \
    {                                                                                \
        asm volatile("s_waitcnt vmcnt(12)" ::: "memory");                            \
        __builtin_amdgcn_s_barrier();                                                \
        asm volatile("" ::: "memory");                                               \
    }

    STAGE(0);
    LOADB(0, B0);
    STAGE(1);
    STAGE(2);

#pragma unroll 1
    for (int t = 0; t < NT; t += 2) {
        WAITBAR();                       // buf[t] ready across all waves
        if (t + 3 < NT) STAGE(t + 3);
        LOADB(t + 1, B1);                // t+1 <= NT-1 always
        COMP(t & 3, B0);
        WAITBAR();                       // buf[t+1] ready
        if (t + 4 < NT) STAGE(t + 4);
        if (t + 2 < NT) LOADB(t + 2, B0);
        COMP((t + 1) & 3, B1);
    }

    float bv[4];
#pragma unroll
    for (int n = 0; n < 4; ++n) bv[n] = bias[col0 + n * 16 + (lane & 15)];
    int rbase = row0 + ((lane >> 4) * 4);
    int cbase = col0 + (lane & 15);
#pragma unroll
    for (int m = 0; m < 4; ++m)
#pragma unroll
        for (int n = 0; n < 4; ++n)
#pragma unroll
            for (int r = 0; r < 4; ++r) {
                int row = rbase + m * 16 + r;
                if (row < N_NODES) {
                    float v = acc[m][n][r] + bv[n];
                    v = v > 0.f ? v : 0.f;
                    int colc = cbase + n * 16;
                    if (EPI) {
                        char* ep = E + ((size_t)(row >> 6) * 8 + 4 + (colc >> 6)) * 8192 +
                                   (row & 63) * 128 + (((colc & 63) * 2) ^ ((row & 7) << 4));
                        *(_Float16*)ep = (_Float16)v;
                    } else {
                        out[(size_t)row * 256 + colc] = (_Float16)v;
                    }
                }
            }
#undef STAGE
#undef LOADB
#undef COMP
#undef WAITBAR
}

// ---------------- sorted-batch graph pooling over f16 H2 ----------------
__global__ void pool_k(const _Float16* __restrict__ H2, const int* __restrict__ batch,
                       float* __restrict__ g_acc) {
    int t = threadIdx.x;
    int i0 = blockIdx.x * 256;
    if (i0 >= N_NODES) return;
    int iend = i0 + 256 < N_NODES ? i0 + 256 : N_NODES;
    int cur = batch[i0];
    float run = 0.f;
    for (int i = i0; i < iend; ++i) {
        int b = batch[i];
        if (b != cur) {
            atomicAdd(&g_acc[cur * HID + t], run);
            run = 0.f;
            cur = b;
        }
        run += (float)H2[(size_t)i * HID + t];
    }
    atomicAdd(&g_acc[cur * HID + t], run);
}

// ---------------- final: out = (g_acc/cnt) @ Wo + bo ----------------
__global__ void final_k(const float* __restrict__ g_acc, const int* __restrict__ gcnt,
                        const float* __restrict__ Wo, const float* __restrict__ bo,
                        void* __restrict__ out, const int* __restrict__ flag) {
    __shared__ float gm[HID];
    __shared__ float red[HID];
    int g = blockIdx.x, t = threadIdx.x;
    float inv = 1.0f / (float)imax(gcnt[g], 1);
    gm[t] = g_acc[g * HID + t] * inv;
    __syncthreads();
    int bf = *flag;
    for (int c = 0; c < NCLS; ++c) {
        red[t] = gm[t] * Wo[t * NCLS + c];
        __syncthreads();
        for (int s = HID / 2; s > 0; s >>= 1) {
            if (t < s) red[t] += red[t + s];
            __syncthreads();
        }
        if (t == 0) {
            float o = red[0] + bo[c];
            if (bf) ((__hip_bfloat16*)out)[g * NCLS + c] = __float2bfloat16(o);
            else    ((float*)out)[g * NCLS + c] = o;
        }
        __syncthreads();
    }
}

extern "C" void kernel_launch(void* const* d_in, const int* in_sizes, int n_in,
                              void* d_out, int out_size, void* d_ws, size_t ws_size,
                              hipStream_t stream) {
    const int* x     = (const int*)d_in[0];
    const int* ei    = (const int*)d_in[1];
    const int* batch = (const int*)d_in[2];
    const int* srcp = ei;
    const int* dstp = ei + N_EDGES;

    // ---- ws layout ----
    char* w = (char*)d_ws;
    auto alloc = [&](size_t bytes) -> char* {
        char* p = w;
        w += (bytes + 255) & ~(size_t)255;
        return p;
    };
    int* flag = (int*)alloc(256);
    const int ZWORDS = N_NODES + N_GRAPHS + N_GRAPHS * HID;  // deg | gcnt | g_acc
    int* zbase = (int*)alloc((size_t)ZWORDS * 4);
    int* deg = zbase;
    int* gcnt = zbase + N_NODES;
    float* g_acc = (float*)(zbase + N_NODES + N_GRAPHS);
    int* row_ptr = (int*)alloc((size_t)(N_NODES + 1) * 4);
    int* nxt     = (int*)alloc((size_t)N_NODES * 4);
    int* bsum    = (int*)alloc(256);
    int* col     = (int*)alloc((size_t)N_EDGES * 4);
    float* Wf    = (float*)alloc((size_t)204810 * 4);
    ushort* W1t  = (ushort*)alloc((size_t)256 * 384 * 2);
    _Float16* W2t = (_Float16*)alloc((size_t)256 * 512 * 2);
    char* A1c    = alloc((size_t)(NPAD / 64) * 6 * 8192);   // swizzled bf16 [M1 ilv | H0]
    char* A2c    = alloc((size_t)(NPAD / 64) * 8 * 8192);   // swizzled f16 [M2 | H1]
    alloc(4096);                                            // pad
    _Float16* H2 = (_Float16*)A1c;  // A1 dead after gemm1; reuse for f16 H2 [N][256]

    const long long cum[10] = {0, 5120, 37888, 70656, 70912, 136448, 201984, 202240, 204800, 204810};
    float* embW = Wf + cum[0];
    float* b1   = Wf + cum[3];
    float* b2   = Wf + cum[6];
    float* Wo   = Wf + cum[7];
    float* bo   = Wf + cum[8];

    // ---- pipeline ----
    detect_k<<<1, 64, 0, stream>>>((const unsigned short*)d_in[3], flag);
    zero_k<<<(ZWORDS + 255) / 256, 256, 0, stream>>>(zbase, ZWORDS);

    ConvArgs ca;
    for (int i = 0; i < 9; ++i) ca.src[i] = d_in[3 + i];
    for (int i = 0; i < 10; ++i) ca.cum[i] = cum[i];
    convert_k<<<801, 256, 0, stream>>>(ca, Wf, flag);

    pack_w_k<<<(256 * 384 + 256 * 512 + 255) / 256, 256, 0, stream>>>(Wf, W1t, W2t);
    embed_k<<<(N_NODES * 64 + 255) / 256, 256, 0, stream>>>(x, embW, A1c);

    hist_edges_k<<<(N_EDGES + 255) / 256, 256, 0, stream>>>(dstp, deg);
    hist_batch_k<<<(N_NODES + 255) / 256, 256, 0, stream>>>(batch, gcnt);

    const int SBLK = (N_NODES + 1 + 1023) / 1024;  // 49
    scan_a_k<<<SBLK, 1024, 0, stream>>>(deg, row_ptr, bsum);
    scan_b_k<<<1, 64, 0, stream>>>(bsum, SBLK);
    scan_c_k<<<SBLK, 1024, 0, stream>>>(row_ptr, bsum, nxt);
    scatter_k<<<(N_EDGES + 255) / 256, 256, 0, stream>>>(srcp, dstp, nxt, col);

    const int GB = NPAD / 64;  // 782
    // layer 1 (bf16 exact: M1 hi/lo + H0; writes H1 f16 into A2 tiles 4-7)
    agg1_k<<<(N_NODES * 64 + 255) / 256, 256, 0, stream>>>(row_ptr, col, x, embW, A1c);
    gemm_mfma_k<384, 1, false><<<GB, 256, 0, stream>>>(A1c, W1t, b1, nullptr, A2c);
    // layer 2 (f16: M2 + H1, K=512)
    agg2_k<<<(N_NODES * 64 + 255) / 256, 256, 0, stream>>>(row_ptr, col, A2c);
    gemm_mfma_k<512, 0, true><<<GB, 256, 0, stream>>>(A2c, (const ushort*)W2t, b2, H2, nullptr);

    // pooling + classifier
    pool_k<<<(N_NODES + 255) / 256, 256, 0, stream>>>(H2, batch, g_acc);
    final_k<<<N_GRAPHS, HID, 0, stream>>>(g_acc, gcnt, Wo, bo, d_out, flag);

    (void)in_sizes; (void)n_in; (void)out_size; (void)ws_size;
}